// Round 14
// baseline (567.132 us; speedup 1.0000x reference)
//
#include <hip/hip_runtime.h>
#include <stdint.h>

#define B_IMG 64
#define NIMG 128
#define NS 576
#define NT 1024
#define DSZ 1024
#define DT 1152
#define TEMPR 0.02f

typedef float f32x4 __attribute__((ext_vector_type(4)));
typedef __bf16 bf16x8 __attribute__((ext_vector_type(8)));
typedef long long i64x2 __attribute__((ext_vector_type(2)));

// ---------- ws layout ----------
constexpr size_t OFF_PROJ = 0;                               // bf16 proj [NIMG][NT][DSZ]
constexpr size_t SZ_PROJ = (size_t)NIMG * NT * DSZ * 2;
constexpr size_t OFF_WT8 = OFF_PROJ + SZ_PROJ;               // fp8 W^T interleaved, x16
constexpr size_t SZ_WT8 = (size_t)DSZ * DT;
constexpr size_t OFF_ACC = OFF_WT8 + SZ_WT8;                 // 2 x f32 (contr, kd)
constexpr size_t OFF_TEA8 = (OFF_ACC + 271) & ~(size_t)255;  // fp8 tea interleaved, x16
constexpr size_t SZ_TEA8 = (size_t)NIMG * NT * DT;
constexpr size_t WS_NEED = OFF_TEA8 + SZ_TEA8;

// Interleaved fp8 layout: byte (row, k) lives at
//   row*1152 + (k>>6)*64 + ((k>>3)&3)*16 + ((k>>5)&1)*8 + (k&7)
// i.e. 16B chunk (row, j, s) = fragment(row,s,kt=2j) || fragment(row,s,kt=2j+1).
// This makes GEMM fragment reads 16B ds_read_b128 (conflict-free swizzlable).

// ---------- helpers ----------
__device__ __forceinline__ unsigned short f2bf(float f) {
  union { float f; uint32_t u; } c; c.f = f;
  uint32_t u = c.u;
  uint32_t r = u + 0x7FFFu + ((u >> 16) & 1u);
  return (unsigned short)(r >> 16);
}
__device__ __forceinline__ float bf2f(unsigned short b) {
  union { float f; uint32_t u; } c; c.u = ((uint32_t)b) << 16;
  return c.f;
}
// manual f32 -> e4m3fn (RNE, saturate at 448, FTZ below 2^-6)
__device__ __forceinline__ uint32_t f2e4m3_1(float x) {
  uint32_t u = __float_as_uint(x);
  uint32_t s = (u >> 31) << 7;
  uint32_t mag = u & 0x7fffffffu;
  if (mag >= 0x43D80000u) return s | 0x7E;
  if (mag < 0x3C800000u) return s;
  uint32_t r = mag + 0x0007FFFFu + ((mag >> 20) & 1u);
  return s | ((r >> 20) - 960u);
}
__device__ __forceinline__ uint32_t cvt4_fp8(float a, float b, float c, float d) {
#if __has_builtin(__builtin_amdgcn_cvt_pk_fp8_f32)
  int v = __builtin_amdgcn_cvt_pk_fp8_f32(a, b, 0, false);
  v = __builtin_amdgcn_cvt_pk_fp8_f32(c, d, v, true);
  return (uint32_t)v;
#else
  return f2e4m3_1(a) | (f2e4m3_1(b) << 8) | (f2e4m3_1(c) << 16) | (f2e4m3_1(d) << 24);
#endif
}
__device__ __forceinline__ void async16(unsigned char* lds, const unsigned char* g) {
  __builtin_amdgcn_global_load_lds(
      (const __attribute__((address_space(1))) unsigned int*)g,
      (__attribute__((address_space(3))) unsigned int*)lds, 16, 0, 0);
}

// ---------- small kernels ----------
__global__ void initAccK(float* accf) {
  if (threadIdx.x == 0) { accf[0] = 0.f; accf[1] = 0.f; }
}

// teacher f32 -> fp8 e4m3 (x16), INTERLEAVED layout; one 8-elem fragment/thread
__global__ __launch_bounds__(256) void cvt8K(const float* __restrict__ teaQ,
                                             const float* __restrict__ teaP,
                                             unsigned char* __restrict__ out) {
  size_t i = (size_t)blockIdx.x * 256 + threadIdx.x;   // fragment index
  const size_t half = (size_t)B_IMG * NT * 144;        // fragments per tensor
  const float* src = (i < half) ? teaQ + i * 8 : teaP + (i - half) * 8;
  uint32_t r = (uint32_t)(i / 144);
  uint32_t f = (uint32_t)(i - (size_t)r * 144);
  uint32_t kt = f >> 2, s = f & 3, e = kt & 1, j = kt >> 1;
  const float4* p = (const float4*)src;
  float4 a = p[0], b = p[1];
  uint2 w;
  w.x = cvt4_fp8(a.x * 16.f, a.y * 16.f, a.z * 16.f, a.w * 16.f);
  w.y = cvt4_fp8(b.x * 16.f, b.y * 16.f, b.z * 16.f, b.w * 16.f);
  *(uint2*)(out + (size_t)r * 1152 + j * 64 + s * 16 + e * 8) = w;
}

// W [DT][DSZ] f32 -> Wt8 interleaved [DSZ-rows][1152] fp8 (x16)
__global__ __launch_bounds__(256) void wtK(const float* __restrict__ W,
                                           unsigned char* __restrict__ Wt8) {
  __shared__ float tile[32][33];
  int n0 = blockIdx.x * 32, k0 = blockIdx.y * 32;
  int tx = threadIdx.x & 31, ty = threadIdx.x >> 5;
  #pragma unroll
  for (int i = 0; i < 4; i++)
    tile[ty + i * 8][tx] = W[(size_t)(k0 + ty + i * 8) * DSZ + n0 + tx];
  __syncthreads();
  #pragma unroll
  for (int i = 0; i < 4; i++) {
    int n = n0 + ty + i * 8;
    int k = k0 + tx;
    size_t addr = (size_t)n * 1152 + (k >> 6) * 64 + ((k >> 3) & 3) * 16 +
                  ((k >> 5) & 1) * 8 + (k & 7);
    Wt8[addr] = (unsigned char)f2e4m3_1(tile[tx][ty + i * 8] * 16.f);
  }
}

__global__ __launch_bounds__(64) void contrK(const float* __restrict__ q,
                                             const float* __restrict__ p, float* accf) {
  int i = blockIdx.x, l = threadIdx.x;
  const float4* qi = (const float4*)(q + (size_t)i * DSZ);
  const float4* pj = (const float4*)(p + (size_t)l * DSZ);
  float dot = 0.f;
  for (int k = 0; k < DSZ / 4; k++) {
    float4 a = qi[k], b = pj[k];
    dot += a.x * b.x + a.y * b.y + a.z * b.z + a.w * b.w;
  }
  float s = dot / TEMPR;
  float m = s;
  #pragma unroll
  for (int o = 32; o; o >>= 1) m = fmaxf(m, __shfl_xor(m, o));
  float e = expf(s - m);
  #pragma unroll
  for (int o = 32; o; o >>= 1) e += __shfl_xor(e, o);
  float lse = m + logf(e);
  float sii = __shfl(s, i);
  if (l == 0) atomicAdd(accf, sii - lse);
}

// ---------- 256x256 fp8 GEMM, BK=64, 5-buf ring, ONE barrier per K-pair ----------
// proj = (fp8 tea x16) @ (fp8 W^T x16)^T / 256 + b   (M=NT, K=DT, N=DSZ)
// 8 waves (2Mx4N), wave tile 128x64; 18 tiles in 9 periods (2 tiles/period);
// 5 LDS bufs (160KB, free: regs cap us at 1 block/CU anyway).
// Period P: STAGE(P+4),STAGE(P+5); RD(B,P+1); MFMA(P); RD(A,P+2); MFMA(P+1);
//           lgkm0; vmcnt(4); barrier.   Buffer-disjointness (mod 5):
//   writes (P+4)%5,(P)%5 vs reads (P+1)%5,(P+2)%5 — disjoint; overwritten bufs'
//   reads completed >=1 gated barrier earlier (lgkm0 in every gate).
__global__ __launch_bounds__(512, 2) void gemm256K(
    const unsigned char* __restrict__ tea8, const unsigned char* __restrict__ Wt8,
    const float* __restrict__ bias, unsigned short* __restrict__ proj) {
  // XCD-chunked bijective remap (2048 % 8 == 0): each XCD owns 16 whole images.
  const int bid = blockIdx.x;
  const int lb = (bid & 7) * 256 + (bid >> 3);
  const int b = lb >> 4;
  const int tile = lb & 15;
  const int mt = tile & 3;
  const int nt = tile >> 2;
  const int M0 = mt * 256, N0 = nt * 256;

  __shared__ __align__(16) unsigned char lds[5][2][16384];

  const int t = threadIdx.x;
  const int l = t & 63;
  const int w = t >> 6;
  const int wr = w >> 2;  // 0..1
  const int wc = w & 3;   // 0..3

  f32x4 acc[8][4];
  #pragma unroll
  for (int i = 0; i < 8; i++)
    #pragma unroll
    for (int j = 0; j < 4; j++) acc[i][j] = (f32x4){0.f, 0.f, 0.f, 0.f};

  // staging: 1024 chunks (16B) per operand per buf; thread t covers CI = t, t+512.
  // chunk CI holds fragment-pair (m = CI>>2, s = (CI&3) ^ ((m>>1)&3)).
  const unsigned char* Abase = tea8 + (size_t)(b * NT + M0) * DT;
  const unsigned char* Bbase = Wt8 + (size_t)N0 * DT;
  const unsigned char* gA[2]; const unsigned char* gB[2];
  int st[2];
  #pragma unroll
  for (int r = 0; r < 2; r++) {
    int CI = r * 512 + t;
    int m = CI >> 2;
    int s = (CI & 3) ^ ((m >> 1) & 3);
    gA[r] = Abase + (size_t)m * DT + s * 16;
    gB[r] = Bbase + (size_t)m * DT + s * 16;
    st[r] = CI * 16;
  }

#define STAGE(JJ) {                                      \
    int bf_ = (JJ) % 5; int ko_ = (JJ) * 64;             \
    async16(&lds[bf_][0][st[0]], gA[0] + ko_);           \
    async16(&lds[bf_][0][st[1]], gA[1] + ko_);           \
    async16(&lds[bf_][1][st[0]], gB[0] + ko_);           \
    async16(&lds[bf_][1][st[1]], gB[1] + ko_); }

  // fragment byte offsets (b128, one per (m,s): both e-halves)
  const int s_ = l >> 4;
  int aOff[8], bOff[4];
  #pragma unroll
  for (int mi = 0; mi < 8; mi++) {
    int m = wr * 128 + mi * 16 + (l & 15);
    aOff[mi] = (m * 4 + (s_ ^ ((m >> 1) & 3))) * 16;
  }
  #pragma unroll
  for (int ni = 0; ni < 4; ni++) {
    int n = wc * 64 + ni * 16 + (l & 15);
    bOff[ni] = (n * 4 + (s_ ^ ((n >> 1) & 3))) * 16;
  }

  i64x2 afA[8], bfA[4], afB[8], bfB[4];

#define RD(SET, J1) {                                                       \
    const unsigned char* aS = &lds[(J1) % 5][0][0];                         \
    const unsigned char* bS = &lds[(J1) % 5][1][0];                         \
    _Pragma("unroll")                                                       \
    for (int mi = 0; mi < 8; mi++) af##SET[mi] = *(const i64x2*)&aS[aOff[mi]]; \
    _Pragma("unroll")                                                       \
    for (int ni = 0; ni < 4; ni++) bf##SET[ni] = *(const i64x2*)&bS[bOff[ni]]; }

#define MMT(SET) {                                                          \
    __builtin_amdgcn_s_setprio(1);                                          \
    _Pragma("unroll")                                                       \
    for (int mi = 0; mi < 8; mi++)                                          \
      _Pragma("unroll")                                                     \
      for (int ni = 0; ni < 4; ni++)                                        \
        acc[mi][ni] = __builtin_amdgcn_mfma_f32_16x16x32_fp8_fp8(           \
            af##SET[mi][0], bf##SET[ni][0], acc[mi][ni], 0, 0, 0);          \
    _Pragma("unroll")                                                       \
    for (int mi = 0; mi < 8; mi++)                                          \
      _Pragma("unroll")                                                     \
      for (int ni = 0; ni < 4; ni++)                                        \
        acc[mi][ni] = __builtin_amdgcn_mfma_f32_16x16x32_fp8_fp8(           \
            af##SET[mi][1], bf##SET[ni][1], acc[mi][ni], 0, 0, 0);          \
    __builtin_amdgcn_s_setprio(0); }

#define GATE(VMLIT) {                                                       \
    asm volatile("s_waitcnt lgkmcnt(0)" ::: "memory");                      \
    asm volatile("s_waitcnt vmcnt(" VMLIT ")" ::: "memory");                \
    __builtin_amdgcn_s_barrier();                                           \
    asm volatile("" ::: "memory"); }

#define K_PERIOD(P, DO_STG, DO_RDA, VMLIT) {                                \
    if (DO_STG) { STAGE((P) + 4); STAGE((P) + 5); }                         \
    RD(B, (P) + 1);                                                         \
    MMT(A);                                                                 \
    if (DO_RDA) RD(A, (P) + 2);                                             \
    MMT(B);                                                                 \
    GATE(VMLIT); }

  // prologue: tiles 0..3 staged (16 ops); vmcnt(4) -> tiles 0..2 landed, s3 flying
  STAGE(0); STAGE(1); STAGE(2); STAGE(3);
  GATE("4");
  RD(A, 0);
  // drain tile-0 reads + barrier so period-0's STAGE(5) (buf 0) can't race them
  asm volatile("s_waitcnt lgkmcnt(0)" ::: "memory");
  __builtin_amdgcn_s_barrier();
  asm volatile("" ::: "memory");

  K_PERIOD(0, 1, 1, "4");
  K_PERIOD(2, 1, 1, "4");
  K_PERIOD(4, 1, 1, "4");
  K_PERIOD(6, 1, 1, "4");
  K_PERIOD(8, 1, 1, "4");
  K_PERIOD(10, 1, 1, "4");
  K_PERIOD(12, 1, 1, "4");     // stages tiles 16,17 (last)
  K_PERIOD(14, 0, 1, "0");     // drains s17; reads tiles 15,16
  // final period: tiles 16,17 — no stage, no next-RD, epilogue syncs after
  RD(B, 17);
  MMT(A);
  MMT(B);
#undef K_PERIOD
#undef GATE
#undef MMT
#undef RD
#undef STAGE

  // ---- coalesced epilogue via LDS, 2 halves (8KB wave-private regions) ----
  // XOR bits 5-6 only: offsets stay inside 128-B rows, regions inside w*8192+8191.
  __syncthreads();
  unsigned char* sc = &lds[0][0][0] + w * 8192;
  const int rbase = (l >> 4) * 4;
  const int cl = l & 15;
  #pragma unroll
  for (int h = 0; h < 2; h++) {
    #pragma unroll
    for (int ni = 0; ni < 4; ni++) {
      int col = N0 + wc * 64 + ni * 16 + cl;
      float bv = bias[col];
      #pragma unroll
      for (int mi2 = 0; mi2 < 4; mi2++) {
        #pragma unroll
        for (int r = 0; r < 4; r++) {
          int row = mi2 * 16 + rbase + r;
          int byteoff = row * 128 + ((ni * 32 + cl * 2) ^ (((row >> 2) & 3) << 5));
          *(unsigned short*)(sc + byteoff) =
              f2bf(acc[h * 4 + mi2][ni][r] * 0.00390625f + bv);
        }
      }
    }
    asm volatile("s_waitcnt lgkmcnt(0)" ::: "memory");
    #pragma unroll
    for (int p = 0; p < 8; p++) {
      int row = p * 8 + (l >> 3);
      int byteoff = row * 128 + (((l & 7) * 16) ^ (((row >> 2) & 3) << 5));
      bf16x8 v = *(const bf16x8*)(sc + byteoff);
      int grow = M0 + wr * 128 + h * 64 + row;
      int gcol = N0 + wc * 64 + (l & 7) * 8;
      *(bf16x8*)&proj[((size_t)b * NT + grow) * DSZ + gcol] = v;
    }
    asm volatile("s_waitcnt lgkmcnt(0)" ::: "memory");
  }
}

// ---------- candidate-match + MSE in one pass ----------
__global__ __launch_bounds__(256) void candK(const float* __restrict__ stuQ,
                                             const float* __restrict__ stuP,
                                             const unsigned short* __restrict__ proj,
                                             float* accf) {
  const int l = threadIdx.x & 63;
  const int w = threadIdx.x >> 6;
  const int gw = blockIdx.x * 4 + w;  // 8192 waves x 9 rows = 73728 rows
  float acc = 0.f;
  #pragma unroll 1
  for (int k = 0; k < 9; k++) {
    int rr = gw * 9 + k;
    int b = rr / NS, i = rr - b * NS;
    const float* srow = (b < B_IMG) ? stuQ + ((size_t)b * NS + i) * DSZ
                                    : stuP + ((size_t)(b - B_IMG) * NS + i) * DSZ;
    const float4* sp = (const float4*)(srow + l * 16);
    float4 s0 = sp[0], s1 = sp[1], s2 = sp[2], s3 = sp[3];

    int iy = i / 24, ix = i - iy * 24;
    int ry = iy % 3, rx = ix % 3;
    int jy0, jy1, jx0, jx1;
    if (ry == 0)      { jy0 = jy1 = (4 * iy) / 3; }
    else if (ry == 1) { jy0 = (4 * iy - 1) / 3; jy1 = (4 * iy + 2) / 3; }
    else              { jy0 = jy1 = (4 * iy + 1) / 3; }
    if (rx == 0)      { jx0 = jx1 = (4 * ix) / 3; }
    else if (rx == 1) { jx0 = (4 * ix - 1) / 3; jx1 = (4 * ix + 2) / 3; }
    else              { jx0 = jx1 = (4 * ix + 1) / 3; }

    const unsigned short* pbase = proj + (size_t)b * NT * DSZ;
    float best = __builtin_inff();
    #pragma unroll
    for (int cy = 0; cy < 2; cy++) {
      int jy = cy ? jy1 : jy0;
      if (cy && jy1 == jy0) continue;
      #pragma unroll
      for (int cx = 0; cx < 2; cx++) {
        int jx = cx ? jx1 : jx0;
        if (cx && jx1 == jx0) continue;
        int col = jy * 32 + jx;
        const uint4* pr = (const uint4*)(pbase + (size_t)col * DSZ + l * 16);
        uint4 p0 = pr[0], p1 = pr[1];
        float sq = 0.f;
        {
          float d;
          d = s0.x - bf2f((unsigned short)(p0.x & 0xFFFF)); sq += d * d;
          d = s0.y - bf2f((unsigned short)(p0.x >> 16));    sq += d * d;
          d = s0.z - bf2f((unsigned short)(p0.y & 0xFFFF)); sq += d * d;
          d = s0.w - bf2f((unsigned short)(p0.y >> 16));    sq += d * d;
          d = s1.x - bf2f((unsigned short)(p0.z & 0xFFFF)); sq += d * d;
          d = s1.y - bf2f((unsigned short)(p0.z >> 16));    sq += d * d;
          d = s1.z - bf2f((unsigned short)(p0.w & 0xFFFF)); sq += d * d;
          d = s1.w - bf2f((unsigned short)(p0.w >> 16));    sq += d * d;
          d = s2.x - bf2f((unsigned short)(p1.x & 0xFFFF)); sq += d * d;
          d = s2.y - bf2f((unsigned short)(p1.x >> 16));    sq += d * d;
          d = s2.z - bf2f((unsigned short)(p1.y & 0xFFFF)); sq += d * d;
          d = s2.w - bf2f((unsigned short)(p1.y >> 16));    sq += d * d;
          d = s3.x - bf2f((unsigned short)(p1.z & 0xFFFF)); sq += d * d;
          d = s3.y - bf2f((unsigned short)(p1.z >> 16));    sq += d * d;
          d = s3.z - bf2f((unsigned short)(p1.w & 0xFFFF)); sq += d * d;
          d = s3.w - bf2f((unsigned short)(p1.w >> 16));    sq += d * d;
        }
        #pragma unroll
        for (int o = 32; o; o >>= 1) sq += __shfl_xor(sq, o);
        if (sq < best) best = sq;  // increasing col order => first-occurrence ties
      }
    }
    acc += best;
  }
  __shared__ float red[4];
  if (l == 0) red[w] = acc;
  __syncthreads();
  if (threadIdx.x == 0)
    atomicAdd(accf + 1, red[0] + red[1] + red[2] + red[3]);
}

__global__ void finalK(const float* accf, float* out) {
  float contr = -accf[0] / (float)B_IMG;
  float kd = (accf[1] / (float)(NS * DSZ)) / (2.f * B_IMG + 1e-8f);
  out[0] = contr + kd;
}

extern "C" void kernel_launch(void* const* d_in, const int* in_sizes, int n_in,
                              void* d_out, int out_size, void* d_ws, size_t ws_size,
                              hipStream_t stream) {
  const float* stuQ = (const float*)d_in[0];
  const float* teaQ = (const float*)d_in[1];
  const float* stuP = (const float*)d_in[2];
  const float* teaP = (const float*)d_in[3];
  const float* qreps = (const float*)d_in[4];
  const float* preps = (const float*)d_in[5];
  const float* W = (const float*)d_in[6];
  const float* bias = (const float*)d_in[7];

  if (ws_size < WS_NEED) return;

  char* ws = (char*)d_ws;
  unsigned short* proj = (unsigned short*)(ws + OFF_PROJ);
  unsigned char* Wt8 = (unsigned char*)(ws + OFF_WT8);
  float* accf = (float*)(ws + OFF_ACC);
  unsigned char* tea8 = (unsigned char*)(ws + OFF_TEA8);
  float* out = (float*)d_out;

  initAccK<<<dim3(1), dim3(64), 0, stream>>>(accf);
  wtK<<<dim3(DSZ / 32, DT / 32), dim3(256), 0, stream>>>(W, Wt8);
  cvt8K<<<dim3((int)((size_t)NIMG * NT * 144 / 256)), dim3(256), 0, stream>>>(
      teaQ, teaP, tea8);
  contrK<<<dim3(B_IMG), dim3(64), 0, stream>>>(qreps, preps, accf);

  gemm256K<<<dim3(2048), dim3(512), 0, stream>>>(tea8, Wt8, bias, proj);

  candK<<<dim3(2048), dim3(256), 0, stream>>>(stuQ, stuP, proj, accf);
  finalK<<<dim3(1), dim3(1), 0, stream>>>(accf, out);
}

// Round 15
// 528.188 us; speedup vs baseline: 1.0737x; 1.0737x over previous
//
#include <hip/hip_runtime.h>
#include <stdint.h>

#define B_IMG 64
#define NIMG 128
#define NS 576
#define NT 1024
#define DSZ 1024
#define DT 1152
#define TEMPR 0.02f

typedef float f32x4 __attribute__((ext_vector_type(4)));
typedef long long i64x2 __attribute__((ext_vector_type(2)));

// ---------- ws layout ----------
constexpr size_t OFF_PROJ = 0;                               // fp8 proj [NIMG][NT][DSZ], x16
constexpr size_t SZ_PROJ = (size_t)NIMG * NT * DSZ;
constexpr size_t OFF_WT8 = OFF_PROJ + SZ_PROJ;               // fp8 W^T interleaved, x16
constexpr size_t SZ_WT8 = (size_t)DSZ * DT;
constexpr size_t OFF_ACC = OFF_WT8 + SZ_WT8;                 // 2 x f32 (contr, kd)
constexpr size_t OFF_TEA8 = (OFF_ACC + 271) & ~(size_t)255;  // fp8 tea interleaved, x16
constexpr size_t SZ_TEA8 = (size_t)NIMG * NT * DT;
constexpr size_t WS_NEED = OFF_TEA8 + SZ_TEA8;

// Interleaved fp8 layout (tea8/Wt8): byte (row, k) lives at
//   row*1152 + (k>>6)*64 + ((k>>3)&3)*16 + ((k>>5)&1)*8 + (k&7)
// i.e. 16B chunk (row, j, s) = fragment(row,s,kt=2j) || fragment(row,s,kt=2j+1).
// proj is stored LINEAR fp8 (x16): element (row, n) at row*1024 + n.

// ---------- helpers ----------
// manual f32 -> e4m3fn (RNE, saturate at 448, FTZ below 2^-6)
__device__ __forceinline__ uint32_t f2e4m3_1(float x) {
  uint32_t u = __float_as_uint(x);
  uint32_t s = (u >> 31) << 7;
  uint32_t mag = u & 0x7fffffffu;
  if (mag >= 0x43D80000u) return s | 0x7E;
  if (mag < 0x3C800000u) return s;
  uint32_t r = mag + 0x0007FFFFu + ((mag >> 20) & 1u);
  return s | ((r >> 20) - 960u);
}
// e4m3fn (x16-scaled) -> f32, with /16 folded into the exponent scale.
// Encoder never emits e4m3 denormals; +-0 decode exactly.
__device__ __forceinline__ float dec8(uint32_t b) {
  uint32_t bits = ((b & 0x80u) << 24) | ((b & 0x7Fu) << 20);
  return __uint_as_float(bits) * 0x1p116f;
}
__device__ __forceinline__ uint32_t cvt4_fp8(float a, float b, float c, float d) {
#if __has_builtin(__builtin_amdgcn_cvt_pk_fp8_f32)
  int v = __builtin_amdgcn_cvt_pk_fp8_f32(a, b, 0, false);
  v = __builtin_amdgcn_cvt_pk_fp8_f32(c, d, v, true);
  return (uint32_t)v;
#else
  return f2e4m3_1(a) | (f2e4m3_1(b) << 8) | (f2e4m3_1(c) << 16) | (f2e4m3_1(d) << 24);
#endif
}
__device__ __forceinline__ void async16(unsigned char* lds, const unsigned char* g) {
  __builtin_amdgcn_global_load_lds(
      (const __attribute__((address_space(1))) unsigned int*)g,
      (__attribute__((address_space(3))) unsigned int*)lds, 16, 0, 0);
}

// ---------- small kernels ----------
__global__ void initAccK(float* accf) {
  if (threadIdx.x == 0) { accf[0] = 0.f; accf[1] = 0.f; }
}

// teacher f32 -> fp8 e4m3 (x16), INTERLEAVED layout; one 8-elem fragment/thread
__global__ __launch_bounds__(256) void cvt8K(const float* __restrict__ teaQ,
                                             const float* __restrict__ teaP,
                                             unsigned char* __restrict__ out) {
  size_t i = (size_t)blockIdx.x * 256 + threadIdx.x;   // fragment index
  const size_t half = (size_t)B_IMG * NT * 144;        // fragments per tensor
  const float* src = (i < half) ? teaQ + i * 8 : teaP + (i - half) * 8;
  uint32_t r = (uint32_t)(i / 144);
  uint32_t f = (uint32_t)(i - (size_t)r * 144);
  uint32_t kt = f >> 2, s = f & 3, e = kt & 1, j = kt >> 1;
  const float4* p = (const float4*)src;
  float4 a = p[0], b = p[1];
  uint2 w;
  w.x = cvt4_fp8(a.x * 16.f, a.y * 16.f, a.z * 16.f, a.w * 16.f);
  w.y = cvt4_fp8(b.x * 16.f, b.y * 16.f, b.z * 16.f, b.w * 16.f);
  *(uint2*)(out + (size_t)r * 1152 + j * 64 + s * 16 + e * 8) = w;
}

// W [DT][DSZ] f32 -> Wt8 interleaved [DSZ-rows][1152] fp8 (x16)
__global__ __launch_bounds__(256) void wtK(const float* __restrict__ W,
                                           unsigned char* __restrict__ Wt8) {
  __shared__ float tile[32][33];
  int n0 = blockIdx.x * 32, k0 = blockIdx.y * 32;
  int tx = threadIdx.x & 31, ty = threadIdx.x >> 5;
  #pragma unroll
  for (int i = 0; i < 4; i++)
    tile[ty + i * 8][tx] = W[(size_t)(k0 + ty + i * 8) * DSZ + n0 + tx];
  __syncthreads();
  #pragma unroll
  for (int i = 0; i < 4; i++) {
    int n = n0 + ty + i * 8;
    int k = k0 + tx;
    size_t addr = (size_t)n * 1152 + (k >> 6) * 64 + ((k >> 3) & 3) * 16 +
                  ((k >> 5) & 1) * 8 + (k & 7);
    Wt8[addr] = (unsigned char)f2e4m3_1(tile[tx][ty + i * 8] * 16.f);
  }
}

__global__ __launch_bounds__(64) void contrK(const float* __restrict__ q,
                                             const float* __restrict__ p, float* accf) {
  int i = blockIdx.x, l = threadIdx.x;
  const float4* qi = (const float4*)(q + (size_t)i * DSZ);
  const float4* pj = (const float4*)(p + (size_t)l * DSZ);
  float dot = 0.f;
  for (int k = 0; k < DSZ / 4; k++) {
    float4 a = qi[k], b = pj[k];
    dot += a.x * b.x + a.y * b.y + a.z * b.z + a.w * b.w;
  }
  float s = dot / TEMPR;
  float m = s;
  #pragma unroll
  for (int o = 32; o; o >>= 1) m = fmaxf(m, __shfl_xor(m, o));
  float e = expf(s - m);
  #pragma unroll
  for (int o = 32; o; o >>= 1) e += __shfl_xor(e, o);
  float lse = m + logf(e);
  float sii = __shfl(s, i);
  if (l == 0) atomicAdd(accf, sii - lse);
}

// ---------- 256x256 fp8 GEMM, BK=64, conflict-free b128 fragment reads ----------
// proj8 = fp8x16( ((fp8 tea x16) @ (fp8 W^T x16)^T)/256 + b )   (M=NT, K=DT, N=DSZ)
// 8 waves (2Mx4N), wave tile 128x64; 18 j-iters (K-tile pairs); 3 LDS bufs (96KB);
// LDS chunk CI = m*4 + (s ^ ((m>>1)&3)): every 8-lane read group covers 32 banks.
// K-loop schedule IDENTICAL to r13 (proven 259us / MfmaUtil 52%).
__global__ __launch_bounds__(512, 2) void gemm256K(
    const unsigned char* __restrict__ tea8, const unsigned char* __restrict__ Wt8,
    const float* __restrict__ bias, unsigned char* __restrict__ proj8) {
  // XCD-chunked bijective remap (2048 % 8 == 0): each XCD owns 16 whole images.
  const int bid = blockIdx.x;
  const int lb = (bid & 7) * 256 + (bid >> 3);
  const int b = lb >> 4;
  const int tile = lb & 15;
  const int mt = tile & 3;
  const int nt = tile >> 2;
  const int M0 = mt * 256, N0 = nt * 256;

  __shared__ __align__(16) unsigned char lds[3][2][16384];

  const int t = threadIdx.x;
  const int l = t & 63;
  const int w = t >> 6;
  const int wr = w >> 2;  // 0..1
  const int wc = w & 3;   // 0..3

  f32x4 acc[8][4];
  #pragma unroll
  for (int i = 0; i < 8; i++)
    #pragma unroll
    for (int j = 0; j < 4; j++) acc[i][j] = (f32x4){0.f, 0.f, 0.f, 0.f};

  // staging: 1024 chunks (16B) per operand per buf; thread t covers CI = t, t+512.
  // chunk CI holds fragment-pair (m = CI>>2, s = (CI&3) ^ ((m>>1)&3)).
  const unsigned char* Abase = tea8 + (size_t)(b * NT + M0) * DT;
  const unsigned char* Bbase = Wt8 + (size_t)N0 * DT;
  const unsigned char* gA[2]; const unsigned char* gB[2];
  int st[2];
  #pragma unroll
  for (int r = 0; r < 2; r++) {
    int CI = r * 512 + t;
    int m = CI >> 2;
    int s = (CI & 3) ^ ((m >> 1) & 3);
    gA[r] = Abase + (size_t)m * DT + s * 16;
    gB[r] = Bbase + (size_t)m * DT + s * 16;
    st[r] = CI * 16;
  }

#define STAGE(JJ) {                                      \
    int bf_ = (JJ) % 3; int ko_ = (JJ) * 64;             \
    async16(&lds[bf_][0][st[0]], gA[0] + ko_);           \
    async16(&lds[bf_][0][st[1]], gA[1] + ko_);           \
    async16(&lds[bf_][1][st[0]], gB[0] + ko_);           \
    async16(&lds[bf_][1][st[1]], gB[1] + ko_); }

  // fragment byte offsets (b128, one per (m,s): both e-halves)
  const int s_ = l >> 4;
  int aOff[8], bOff[4];
  #pragma unroll
  for (int mi = 0; mi < 8; mi++) {
    int m = wr * 128 + mi * 16 + (l & 15);
    aOff[mi] = (m * 4 + (s_ ^ ((m >> 1) & 3))) * 16;
  }
  #pragma unroll
  for (int ni = 0; ni < 4; ni++) {
    int n = wc * 64 + ni * 16 + (l & 15);
    bOff[ni] = (n * 4 + (s_ ^ ((n >> 1) & 3))) * 16;
  }

  i64x2 afA[8], bfA[4], afB[8], bfB[4];

#define RD(SET, J1) {                                                       \
    const unsigned char* aS = &lds[(J1) % 3][0][0];                         \
    const unsigned char* bS = &lds[(J1) % 3][1][0];                         \
    _Pragma("unroll")                                                       \
    for (int mi = 0; mi < 8; mi++) af##SET[mi] = *(const i64x2*)&aS[aOff[mi]]; \
    _Pragma("unroll")                                                       \
    for (int ni = 0; ni < 4; ni++) bf##SET[ni] = *(const i64x2*)&bS[bOff[ni]]; }

#define MM(SET, E) {                                                        \
    __builtin_amdgcn_s_setprio(1);                                          \
    _Pragma("unroll")                                                       \
    for (int mi = 0; mi < 8; mi++)                                          \
      _Pragma("unroll")                                                     \
      for (int ni = 0; ni < 4; ni++)                                        \
        acc[mi][ni] = __builtin_amdgcn_mfma_f32_16x16x32_fp8_fp8(           \
            af##SET[mi][E], bf##SET[ni][E], acc[mi][ni], 0, 0, 0);          \
    __builtin_amdgcn_s_setprio(0); }

#define K_ITER(JT, VMLIT, DO_STG, DO_READ, CUR, NXT) {                      \
    asm volatile("s_waitcnt lgkmcnt(0)" ::: "memory");                      \
    asm volatile("s_waitcnt vmcnt(" VMLIT ")" ::: "memory");                \
    __builtin_amdgcn_s_barrier();                                           \
    asm volatile("" ::: "memory");                                          \
    if (DO_STG) STAGE((JT) + 3);                                            \
    if (DO_READ) RD(NXT, (JT) + 1);                                         \
    MM(CUR, 0); MM(CUR, 1); }

  // prologue: 3 k-pair tiles staged (4 ops each = 12); drain tile0 -> vmcnt(8)
  STAGE(0); STAGE(1); STAGE(2);
  asm volatile("s_waitcnt vmcnt(8)" ::: "memory");
  __builtin_amdgcn_s_barrier();
  asm volatile("" ::: "memory");
  RD(A, 0);

  for (int j = 0; j < 14; j += 2) {
    K_ITER(j, "4", true, true, A, B);
    K_ITER(j + 1, "4", true, true, B, A);
  }
  K_ITER(14, "4", true, true, A, B);    // stages tile 17 (last)
  K_ITER(15, "4", false, true, B, A);
  K_ITER(16, "0", false, true, A, B);
  K_ITER(17, "0", false, false, B, A);
#undef K_ITER
#undef MM
#undef RD
#undef STAGE

  // ---- coalesced fp8 epilogue via LDS (8KB wave-private regions) ----
  // stored value = 16 * (acc/256 + bias) = acc*0.0625 + 16*bias.
  // scatter: 1 byte per acc element at row*64 + col (row in [0,128), col in [0,64)).
  // gather: 8B per lane -> 8B global stores (8 lanes cover a 64B row segment).
  __syncthreads();
  unsigned char* sc = &lds[0][0][0] + w * 8192;
  const int rbase = (l >> 4) * 4;
  const int cl = l & 15;
  #pragma unroll
  for (int ni = 0; ni < 4; ni++) {
    int col = N0 + wc * 64 + ni * 16 + cl;
    float bv16 = bias[col] * 16.f;
    #pragma unroll
    for (int mi = 0; mi < 8; mi++) {
      #pragma unroll
      for (int r = 0; r < 4; r++) {
        int row = mi * 16 + rbase + r;
        sc[row * 64 + ni * 16 + cl] =
            (unsigned char)f2e4m3_1(acc[mi][ni][r] * 0.0625f + bv16);
      }
    }
  }
  asm volatile("s_waitcnt lgkmcnt(0)" ::: "memory");
  #pragma unroll
  for (int p = 0; p < 16; p++) {
    int row = p * 8 + (l >> 3);
    long long v = *(const long long*)(sc + row * 64 + (l & 7) * 8);
    int grow = M0 + wr * 128 + row;
    int gcol = N0 + wc * 64 + (l & 7) * 8;
    *(long long*)&proj8[((size_t)b * NT + grow) * DSZ + gcol] = v;
  }
}

// ---------- candidate-match + MSE in one pass (fp8 proj) ----------
__global__ __launch_bounds__(256) void candK(const float* __restrict__ stuQ,
                                             const float* __restrict__ stuP,
                                             const unsigned char* __restrict__ proj8,
                                             float* accf) {
  const int l = threadIdx.x & 63;
  const int w = threadIdx.x >> 6;
  const int gw = blockIdx.x * 4 + w;  // 8192 waves x 9 rows = 73728 rows
  float acc = 0.f;
  #pragma unroll 1
  for (int k = 0; k < 9; k++) {
    int rr = gw * 9 + k;
    int b = rr / NS, i = rr - b * NS;
    const float* srow = (b < B_IMG) ? stuQ + ((size_t)b * NS + i) * DSZ
                                    : stuP + ((size_t)(b - B_IMG) * NS + i) * DSZ;
    const float4* sp = (const float4*)(srow + l * 16);
    float4 s0 = sp[0], s1 = sp[1], s2 = sp[2], s3 = sp[3];

    int iy = i / 24, ix = i - iy * 24;
    int ry = iy % 3, rx = ix % 3;
    int jy0, jy1, jx0, jx1;
    if (ry == 0)      { jy0 = jy1 = (4 * iy) / 3; }
    else if (ry == 1) { jy0 = (4 * iy - 1) / 3; jy1 = (4 * iy + 2) / 3; }
    else              { jy0 = jy1 = (4 * iy + 1) / 3; }
    if (rx == 0)      { jx0 = jx1 = (4 * ix) / 3; }
    else if (rx == 1) { jx0 = (4 * ix - 1) / 3; jx1 = (4 * ix + 2) / 3; }
    else              { jx0 = jx1 = (4 * ix + 1) / 3; }

    const unsigned char* pbase = proj8 + (size_t)b * NT * DSZ;
    float best = __builtin_inff();
    #pragma unroll
    for (int cy = 0; cy < 2; cy++) {
      int jy = cy ? jy1 : jy0;
      if (cy && jy1 == jy0) continue;
      #pragma unroll
      for (int cx = 0; cx < 2; cx++) {
        int jx = cx ? jx1 : jx0;
        if (cx && jx1 == jx0) continue;
        int col = jy * 32 + jx;
        uint4 p0 = *(const uint4*)(pbase + (size_t)col * DSZ + l * 16);
        float sq = 0.f;
        {
          float d;
          d = s0.x - dec8(p0.x & 0xFF);         sq += d * d;
          d = s0.y - dec8((p0.x >> 8) & 0xFF);  sq += d * d;
          d = s0.z - dec8((p0.x >> 16) & 0xFF); sq += d * d;
          d = s0.w - dec8(p0.x >> 24);          sq += d * d;
          d = s1.x - dec8(p0.y & 0xFF);         sq += d * d;
          d = s1.y - dec8((p0.y >> 8) & 0xFF);  sq += d * d;
          d = s1.z - dec8((p0.y >> 16) & 0xFF); sq += d * d;
          d = s1.w - dec8(p0.y >> 24);          sq += d * d;
          d = s2.x - dec8(p0.z & 0xFF);         sq += d * d;
          d = s2.y - dec8((p0.z >> 8) & 0xFF);  sq += d * d;
          d = s2.z - dec8((p0.z >> 16) & 0xFF); sq += d * d;
          d = s2.w - dec8(p0.z >> 24);          sq += d * d;
          d = s3.x - dec8(p0.w & 0xFF);         sq += d * d;
          d = s3.y - dec8((p0.w >> 8) & 0xFF);  sq += d * d;
          d = s3.z - dec8((p0.w >> 16) & 0xFF); sq += d * d;
          d = s3.w - dec8(p0.w >> 24);          sq += d * d;
        }
        #pragma unroll
        for (int o = 32; o; o >>= 1) sq += __shfl_xor(sq, o);
        if (sq < best) best = sq;  // increasing col order => first-occurrence ties
      }
    }
    acc += best;
  }
  __shared__ float red[4];
  if (l == 0) red[w] = acc;
  __syncthreads();
  if (threadIdx.x == 0)
    atomicAdd(accf + 1, red[0] + red[1] + red[2] + red[3]);
}

__global__ void finalK(const float* accf, float* out) {
  float contr = -accf[0] / (float)B_IMG;
  float kd = (accf[1] / (float)(NS * DSZ)) / (2.f * B_IMG + 1e-8f);
  out[0] = contr + kd;
}

extern "C" void kernel_launch(void* const* d_in, const int* in_sizes, int n_in,
                              void* d_out, int out_size, void* d_ws, size_t ws_size,
                              hipStream_t stream) {
  const float* stuQ = (const float*)d_in[0];
  const float* teaQ = (const float*)d_in[1];
  const float* stuP = (const float*)d_in[2];
  const float* teaP = (const float*)d_in[3];
  const float* qreps = (const float*)d_in[4];
  const float* preps = (const float*)d_in[5];
  const float* W = (const float*)d_in[6];
  const float* bias = (const float*)d_in[7];

  if (ws_size < WS_NEED) return;

  char* ws = (char*)d_ws;
  unsigned char* proj8 = (unsigned char*)(ws + OFF_PROJ);
  unsigned char* Wt8 = (unsigned char*)(ws + OFF_WT8);
  float* accf = (float*)(ws + OFF_ACC);
  unsigned char* tea8 = (unsigned char*)(ws + OFF_TEA8);
  float* out = (float*)d_out;

  initAccK<<<dim3(1), dim3(64), 0, stream>>>(accf);
  wtK<<<dim3(DSZ / 32, DT / 32), dim3(256), 0, stream>>>(W, Wt8);
  cvt8K<<<dim3((int)((size_t)NIMG * NT * 144 / 256)), dim3(256), 0, stream>>>(
      teaQ, teaP, tea8);
  contrK<<<dim3(B_IMG), dim3(64), 0, stream>>>(qreps, preps, accf);

  gemm256K<<<dim3(2048), dim3(512), 0, stream>>>(tea8, Wt8, bias, proj8);

  candK<<<dim3(2048), dim3(256), 0, stream>>>(stuQ, stuP, proj8, accf);
  finalK<<<dim3(1), dim3(1), 0, stream>>>(accf, out);
}

// Round 16
// 493.028 us; speedup vs baseline: 1.1503x; 1.0713x over previous
//
#include <hip/hip_runtime.h>
#include <stdint.h>

#define B_IMG 64
#define NIMG 128
#define NS 576
#define NT 1024
#define DSZ 1024
#define DT 1152
#define TEMPR 0.02f

typedef float f32x4 __attribute__((ext_vector_type(4)));
typedef unsigned short u16x8 __attribute__((ext_vector_type(8)));
typedef long long i64x2 __attribute__((ext_vector_type(2)));

// ---------- ws layout ----------
constexpr size_t OFF_PROJ = 0;                               // fp8 proj [NIMG][NT][DSZ], x16
constexpr size_t SZ_PROJ = (size_t)NIMG * NT * DSZ;
constexpr size_t OFF_WT8 = OFF_PROJ + SZ_PROJ;               // fp8 W^T interleaved, x16
constexpr size_t SZ_WT8 = (size_t)DSZ * DT;
constexpr size_t OFF_ACC = OFF_WT8 + SZ_WT8;                 // 2 x f32 (contr, kd)
constexpr size_t OFF_TEA8 = (OFF_ACC + 271) & ~(size_t)255;  // fp8 tea interleaved, x16
constexpr size_t SZ_TEA8 = (size_t)NIMG * NT * DT;
constexpr size_t WS_NEED = OFF_TEA8 + SZ_TEA8;

// Interleaved fp8 layout (tea8/Wt8): byte (row, k) lives at
//   row*1152 + (k>>6)*64 + ((k>>3)&3)*16 + ((k>>5)&1)*8 + (k&7)
// i.e. 16B chunk (row, j, s) = fragment(row,s,kt=2j) || fragment(row,s,kt=2j+1).
// proj is stored LINEAR fp8 (x16): element (row, n) at row*1024 + n.

// ---------- helpers ----------
__device__ __forceinline__ unsigned short f2bf(float f) {
  union { float f; uint32_t u; } c; c.f = f;
  uint32_t u = c.u;
  uint32_t r = u + 0x7FFFu + ((u >> 16) & 1u);
  return (unsigned short)(r >> 16);
}
__device__ __forceinline__ float bf2f(unsigned short b) {
  union { float f; uint32_t u; } c; c.u = ((uint32_t)b) << 16;
  return c.f;
}
// manual f32 -> e4m3fn (RNE, saturate at 448, FTZ below 2^-6)
__device__ __forceinline__ uint32_t f2e4m3_1(float x) {
  uint32_t u = __float_as_uint(x);
  uint32_t s = (u >> 31) << 7;
  uint32_t mag = u & 0x7fffffffu;
  if (mag >= 0x43D80000u) return s | 0x7E;
  if (mag < 0x3C800000u) return s;
  uint32_t r = mag + 0x0007FFFFu + ((mag >> 20) & 1u);
  return s | ((r >> 20) - 960u);
}
// e4m3fn (x16-scaled) -> f32, with /16 folded into the exponent scale.
// Encoder never emits e4m3 denormals; +-0 decode exactly.
__device__ __forceinline__ float dec8(uint32_t b) {
  uint32_t bits = ((b & 0x80u) << 24) | ((b & 0x7Fu) << 20);
  return __uint_as_float(bits) * 0x1p116f;
}
__device__ __forceinline__ uint32_t cvt4_fp8(float a, float b, float c, float d) {
#if __has_builtin(__builtin_amdgcn_cvt_pk_fp8_f32)
  int v = __builtin_amdgcn_cvt_pk_fp8_f32(a, b, 0, false);
  v = __builtin_amdgcn_cvt_pk_fp8_f32(c, d, v, true);
  return (uint32_t)v;
#else
  return f2e4m3_1(a) | (f2e4m3_1(b) << 8) | (f2e4m3_1(c) << 16) | (f2e4m3_1(d) << 24);
#endif
}
__device__ __forceinline__ void async16(unsigned char* lds, const unsigned char* g) {
  __builtin_amdgcn_global_load_lds(
      (const __attribute__((address_space(1))) unsigned int*)g,
      (__attribute__((address_space(3))) unsigned int*)lds, 16, 0, 0);
}

// ---------- small kernels ----------
__global__ void initAccK(float* accf) {
  if (threadIdx.x == 0) { accf[0] = 0.f; accf[1] = 0.f; }
}

// teacher f32 -> fp8 e4m3 (x16), INTERLEAVED layout; one 8-elem fragment/thread
__global__ __launch_bounds__(256) void cvt8K(const float* __restrict__ teaQ,
                                             const float* __restrict__ teaP,
                                             unsigned char* __restrict__ out) {
  size_t i = (size_t)blockIdx.x * 256 + threadIdx.x;   // fragment index
  const size_t half = (size_t)B_IMG * NT * 144;        // fragments per tensor
  const float* src = (i < half) ? teaQ + i * 8 : teaP + (i - half) * 8;
  uint32_t r = (uint32_t)(i / 144);
  uint32_t f = (uint32_t)(i - (size_t)r * 144);
  uint32_t kt = f >> 2, s = f & 3, e = kt & 1, j = kt >> 1;
  const float4* p = (const float4*)src;
  float4 a = p[0], b = p[1];
  uint2 w;
  w.x = cvt4_fp8(a.x * 16.f, a.y * 16.f, a.z * 16.f, a.w * 16.f);
  w.y = cvt4_fp8(b.x * 16.f, b.y * 16.f, b.z * 16.f, b.w * 16.f);
  *(uint2*)(out + (size_t)r * 1152 + j * 64 + s * 16 + e * 8) = w;
}

// W [DT][DSZ] f32 -> Wt8 interleaved [DSZ-rows][1152] fp8 (x16)
__global__ __launch_bounds__(256) void wtK(const float* __restrict__ W,
                                           unsigned char* __restrict__ Wt8) {
  __shared__ float tile[32][33];
  int n0 = blockIdx.x * 32, k0 = blockIdx.y * 32;
  int tx = threadIdx.x & 31, ty = threadIdx.x >> 5;
  #pragma unroll
  for (int i = 0; i < 4; i++)
    tile[ty + i * 8][tx] = W[(size_t)(k0 + ty + i * 8) * DSZ + n0 + tx];
  __syncthreads();
  #pragma unroll
  for (int i = 0; i < 4; i++) {
    int n = n0 + ty + i * 8;
    int k = k0 + tx;
    size_t addr = (size_t)n * 1152 + (k >> 6) * 64 + ((k >> 3) & 3) * 16 +
                  ((k >> 5) & 1) * 8 + (k & 7);
    Wt8[addr] = (unsigned char)f2e4m3_1(tile[tx][ty + i * 8] * 16.f);
  }
}

__global__ __launch_bounds__(64) void contrK(const float* __restrict__ q,
                                             const float* __restrict__ p, float* accf) {
  int i = blockIdx.x, l = threadIdx.x;
  const float4* qi = (const float4*)(q + (size_t)i * DSZ);
  const float4* pj = (const float4*)(p + (size_t)l * DSZ);
  float dot = 0.f;
  for (int k = 0; k < DSZ / 4; k++) {
    float4 a = qi[k], b = pj[k];
    dot += a.x * b.x + a.y * b.y + a.z * b.z + a.w * b.w;
  }
  float s = dot / TEMPR;
  float m = s;
  #pragma unroll
  for (int o = 32; o; o >>= 1) m = fmaxf(m, __shfl_xor(m, o));
  float e = expf(s - m);
  #pragma unroll
  for (int o = 32; o; o >>= 1) e += __shfl_xor(e, o);
  float lse = m + logf(e);
  float sii = __shfl(s, i);
  if (l == 0) atomicAdd(accf, sii - lse);
}

// ---------- 256x256 fp8 GEMM, BK=64, conflict-free b128 fragment reads ----------
// proj8 = fp8( 16*((fp8 tea x16)@(fp8 W^T x16)^T)/256 + 16*b )  (M=NT,K=DT,N=DSZ)
// 8 waves (2Mx4N), wave tile 128x64; 18 j-iters; 3 LDS bufs (96KB);
// K-loop schedule IDENTICAL to r13 (proven 259us / MfmaUtil 52% / conflicts 0).
// Epilogue: r13's bf16 scatter/gather LDS pattern (conflict-free), with the
// fp8 conversion done in the GATHER phase via HW cvt_pk (8B global stores).
__global__ __launch_bounds__(512, 2) void gemm256K(
    const unsigned char* __restrict__ tea8, const unsigned char* __restrict__ Wt8,
    const float* __restrict__ bias, unsigned char* __restrict__ proj8) {
  // XCD-chunked bijective remap (2048 % 8 == 0): each XCD owns 16 whole images.
  const int bid = blockIdx.x;
  const int lb = (bid & 7) * 256 + (bid >> 3);
  const int b = lb >> 4;
  const int tile = lb & 15;
  const int mt = tile & 3;
  const int nt = tile >> 2;
  const int M0 = mt * 256, N0 = nt * 256;

  __shared__ __align__(16) unsigned char lds[3][2][16384];

  const int t = threadIdx.x;
  const int l = t & 63;
  const int w = t >> 6;
  const int wr = w >> 2;  // 0..1
  const int wc = w & 3;   // 0..3

  f32x4 acc[8][4];
  #pragma unroll
  for (int i = 0; i < 8; i++)
    #pragma unroll
    for (int j = 0; j < 4; j++) acc[i][j] = (f32x4){0.f, 0.f, 0.f, 0.f};

  // staging: 1024 chunks (16B) per operand per buf; thread t covers CI = t, t+512.
  // chunk CI holds fragment-pair (m = CI>>2, s = (CI&3) ^ ((m>>1)&3)).
  const unsigned char* Abase = tea8 + (size_t)(b * NT + M0) * DT;
  const unsigned char* Bbase = Wt8 + (size_t)N0 * DT;
  const unsigned char* gA[2]; const unsigned char* gB[2];
  int st[2];
  #pragma unroll
  for (int r = 0; r < 2; r++) {
    int CI = r * 512 + t;
    int m = CI >> 2;
    int s = (CI & 3) ^ ((m >> 1) & 3);
    gA[r] = Abase + (size_t)m * DT + s * 16;
    gB[r] = Bbase + (size_t)m * DT + s * 16;
    st[r] = CI * 16;
  }

#define STAGE(JJ) {                                      \
    int bf_ = (JJ) % 3; int ko_ = (JJ) * 64;             \
    async16(&lds[bf_][0][st[0]], gA[0] + ko_);           \
    async16(&lds[bf_][0][st[1]], gA[1] + ko_);           \
    async16(&lds[bf_][1][st[0]], gB[0] + ko_);           \
    async16(&lds[bf_][1][st[1]], gB[1] + ko_); }

  // fragment byte offsets (b128, one per (m,s): both e-halves)
  const int s_ = l >> 4;
  int aOff[8], bOff[4];
  #pragma unroll
  for (int mi = 0; mi < 8; mi++) {
    int m = wr * 128 + mi * 16 + (l & 15);
    aOff[mi] = (m * 4 + (s_ ^ ((m >> 1) & 3))) * 16;
  }
  #pragma unroll
  for (int ni = 0; ni < 4; ni++) {
    int n = wc * 64 + ni * 16 + (l & 15);
    bOff[ni] = (n * 4 + (s_ ^ ((n >> 1) & 3))) * 16;
  }

  i64x2 afA[8], bfA[4], afB[8], bfB[4];

#define RD(SET, J1) {                                                       \
    const unsigned char* aS = &lds[(J1) % 3][0][0];                         \
    const unsigned char* bS = &lds[(J1) % 3][1][0];                         \
    _Pragma("unroll")                                                       \
    for (int mi = 0; mi < 8; mi++) af##SET[mi] = *(const i64x2*)&aS[aOff[mi]]; \
    _Pragma("unroll")                                                       \
    for (int ni = 0; ni < 4; ni++) bf##SET[ni] = *(const i64x2*)&bS[bOff[ni]]; }

#define MM(SET, E) {                                                        \
    __builtin_amdgcn_s_setprio(1);                                          \
    _Pragma("unroll")                                                       \
    for (int mi = 0; mi < 8; mi++)                                          \
      _Pragma("unroll")                                                     \
      for (int ni = 0; ni < 4; ni++)                                        \
        acc[mi][ni] = __builtin_amdgcn_mfma_f32_16x16x32_fp8_fp8(           \
            af##SET[mi][E], bf##SET[ni][E], acc[mi][ni], 0, 0, 0);          \
    __builtin_amdgcn_s_setprio(0); }

#define K_ITER(JT, VMLIT, DO_STG, DO_READ, CUR, NXT) {                      \
    asm volatile("s_waitcnt lgkmcnt(0)" ::: "memory");                      \
    asm volatile("s_waitcnt vmcnt(" VMLIT ")" ::: "memory");                \
    __builtin_amdgcn_s_barrier();                                           \
    asm volatile("" ::: "memory");                                          \
    if (DO_STG) STAGE((JT) + 3);                                            \
    if (DO_READ) RD(NXT, (JT) + 1);                                         \
    MM(CUR, 0); MM(CUR, 1); }

  // prologue: 3 k-pair tiles staged (4 ops each = 12); drain tile0 -> vmcnt(8)
  STAGE(0); STAGE(1); STAGE(2);
  asm volatile("s_waitcnt vmcnt(8)" ::: "memory");
  __builtin_amdgcn_s_barrier();
  asm volatile("" ::: "memory");
  RD(A, 0);

  for (int j = 0; j < 14; j += 2) {
    K_ITER(j, "4", true, true, A, B);
    K_ITER(j + 1, "4", true, true, B, A);
  }
  K_ITER(14, "4", true, true, A, B);    // stages tile 17 (last)
  K_ITER(15, "4", false, true, B, A);
  K_ITER(16, "0", false, true, A, B);
  K_ITER(17, "0", false, false, B, A);
#undef K_ITER
#undef MM
#undef RD
#undef STAGE

  // ---- epilogue: r13 bf16 scatter/gather (conflict-free), fp8 on gather ----
  // scatter value = 16*(acc/256 + bias) = acc*0.0625 + 16*bias (bf16, 2B writes,
  // XOR bits 5-6: proven 0-conflict). gather reads bf16x8 (16B, proven pattern),
  // converts to 8 fp8 via HW cvt_pk, stores 8B to proj8.
  __syncthreads();
  unsigned char* sc = &lds[0][0][0] + w * 8192;
  const int rbase = (l >> 4) * 4;
  const int cl = l & 15;
  #pragma unroll
  for (int h = 0; h < 2; h++) {
    #pragma unroll
    for (int ni = 0; ni < 4; ni++) {
      int col = N0 + wc * 64 + ni * 16 + cl;
      float bv16 = bias[col] * 16.f;
      #pragma unroll
      for (int mi2 = 0; mi2 < 4; mi2++) {
        #pragma unroll
        for (int r = 0; r < 4; r++) {
          int row = mi2 * 16 + rbase + r;
          int byteoff = row * 128 + ((ni * 32 + cl * 2) ^ (((row >> 2) & 3) << 5));
          *(unsigned short*)(sc + byteoff) =
              f2bf(acc[h * 4 + mi2][ni][r] * 0.0625f + bv16);
        }
      }
    }
    asm volatile("s_waitcnt lgkmcnt(0)" ::: "memory");
    #pragma unroll
    for (int p = 0; p < 8; p++) {
      int row = p * 8 + (l >> 3);
      int byteoff = row * 128 + (((l & 7) * 16) ^ (((row >> 2) & 3) << 5));
      u16x8 v = *(const u16x8*)(sc + byteoff);
      uint2 wq;
      wq.x = cvt4_fp8(bf2f(v[0]), bf2f(v[1]), bf2f(v[2]), bf2f(v[3]));
      wq.y = cvt4_fp8(bf2f(v[4]), bf2f(v[5]), bf2f(v[6]), bf2f(v[7]));
      int grow = M0 + wr * 128 + h * 64 + row;
      int gcol = N0 + wc * 64 + (l & 7) * 8;
      *(uint2*)&proj8[((size_t)b * NT + grow) * DSZ + gcol] = wq;
    }
    asm volatile("s_waitcnt lgkmcnt(0)" ::: "memory");
  }
}

// ---------- candidate-match + MSE in one pass (fp8 proj) ----------
__global__ __launch_bounds__(256) void candK(const float* __restrict__ stuQ,
                                             const float* __restrict__ stuP,
                                             const unsigned char* __restrict__ proj8,
                                             float* accf) {
  const int l = threadIdx.x & 63;
  const int w = threadIdx.x >> 6;
  const int gw = blockIdx.x * 4 + w;  // 8192 waves x 9 rows = 73728 rows
  float acc = 0.f;
  #pragma unroll 1
  for (int k = 0; k < 9; k++) {
    int rr = gw * 9 + k;
    int b = rr / NS, i = rr - b * NS;
    const float* srow = (b < B_IMG) ? stuQ + ((size_t)b * NS + i) * DSZ
                                    : stuP + ((size_t)(b - B_IMG) * NS + i) * DSZ;
    const float4* sp = (const float4*)(srow + l * 16);
    float4 s0 = sp[0], s1 = sp[1], s2 = sp[2], s3 = sp[3];

    int iy = i / 24, ix = i - iy * 24;
    int ry = iy % 3, rx = ix % 3;
    int jy0, jy1, jx0, jx1;
    if (ry == 0)      { jy0 = jy1 = (4 * iy) / 3; }
    else if (ry == 1) { jy0 = (4 * iy - 1) / 3; jy1 = (4 * iy + 2) / 3; }
    else              { jy0 = jy1 = (4 * iy + 1) / 3; }
    if (rx == 0)      { jx0 = jx1 = (4 * ix) / 3; }
    else if (rx == 1) { jx0 = (4 * ix - 1) / 3; jx1 = (4 * ix + 2) / 3; }
    else              { jx0 = jx1 = (4 * ix + 1) / 3; }

    const unsigned char* pbase = proj8 + (size_t)b * NT * DSZ;
    float best = __builtin_inff();
    #pragma unroll
    for (int cy = 0; cy < 2; cy++) {
      int jy = cy ? jy1 : jy0;
      if (cy && jy1 == jy0) continue;
      #pragma unroll
      for (int cx = 0; cx < 2; cx++) {
        int jx = cx ? jx1 : jx0;
        if (cx && jx1 == jx0) continue;
        int col = jy * 32 + jx;
        uint4 p0 = *(const uint4*)(pbase + (size_t)col * DSZ + l * 16);
        float sq = 0.f;
        {
          float d;
          d = s0.x - dec8(p0.x & 0xFF);         sq += d * d;
          d = s0.y - dec8((p0.x >> 8) & 0xFF);  sq += d * d;
          d = s0.z - dec8((p0.x >> 16) & 0xFF); sq += d * d;
          d = s0.w - dec8(p0.x >> 24);          sq += d * d;
          d = s1.x - dec8(p0.y & 0xFF);         sq += d * d;
          d = s1.y - dec8((p0.y >> 8) & 0xFF);  sq += d * d;
          d = s1.z - dec8((p0.y >> 16) & 0xFF); sq += d * d;
          d = s1.w - dec8(p0.y >> 24);          sq += d * d;
          d = s2.x - dec8(p0.z & 0xFF);         sq += d * d;
          d = s2.y - dec8((p0.z >> 8) & 0xFF);  sq += d * d;
          d = s2.z - dec8((p0.z >> 16) & 0xFF); sq += d * d;
          d = s2.w - dec8(p0.z >> 24);          sq += d * d;
          d = s3.x - dec8(p0.w & 0xFF);         sq += d * d;
          d = s3.y - dec8((p0.w >> 8) & 0xFF);  sq += d * d;
          d = s3.z - dec8((p0.w >> 16) & 0xFF); sq += d * d;
          d = s3.w - dec8(p0.w >> 24);          sq += d * d;
        }
        #pragma unroll
        for (int o = 32; o; o >>= 1) sq += __shfl_xor(sq, o);
        if (sq < best) best = sq;  // increasing col order => first-occurrence ties
      }
    }
    acc += best;
  }
  __shared__ float red[4];
  if (l == 0) red[w] = acc;
  __syncthreads();
  if (threadIdx.x == 0)
    atomicAdd(accf + 1, red[0] + red[1] + red[2] + red[3]);
}

__global__ void finalK(const float* accf, float* out) {
  float contr = -accf[0] / (float)B_IMG;
  float kd = (accf[1] / (float)(NS * DSZ)) / (2.f * B_IMG + 1e-8f);
  out[0] = contr + kd;
}

extern "C" void kernel_launch(void* const* d_in, const int* in_sizes, int n_in,
                              void* d_out, int out_size, void* d_ws, size_t ws_size,
                              hipStream_t stream) {
  const float* stuQ = (const float*)d_in[0];
  const float* teaQ = (const float*)d_in[1];
  const float* stuP = (const float*)d_in[2];
  const float* teaP = (const float*)d_in[3];
  const float* qreps = (const float*)d_in[4];
  const float* preps = (const float*)d_in[5];
  const float* W = (const float*)d_in[6];
  const float* bias = (const float*)d_in[7];

  if (ws_size < WS_NEED) return;

  char* ws = (char*)d_ws;
  unsigned char* proj8 = (unsigned char*)(ws + OFF_PROJ);
  unsigned char* Wt8 = (unsigned char*)(ws + OFF_WT8);
  float* accf = (float*)(ws + OFF_ACC);
  unsigned char* tea8 = (unsigned char*)(ws + OFF_TEA8);
  float* out = (float*)d_out;

  initAccK<<<dim3(1), dim3(64), 0, stream>>>(accf);
  wtK<<<dim3(DSZ / 32, DT / 32), dim3(256), 0, stream>>>(W, Wt8);
  cvt8K<<<dim3((int)((size_t)NIMG * NT * 144 / 256)), dim3(256), 0, stream>>>(
      teaQ, teaP, tea8);
  contrK<<<dim3(B_IMG), dim3(64), 0, stream>>>(qreps, preps, accf);

  gemm256K<<<dim3(2048), dim3(512), 0, stream>>>(tea8, Wt8, bias, proj8);

  candK<<<dim3(2048), dim3(256), 0, stream>>>(stuQ, stuP, proj8, accf);
  finalK<<<dim3(1), dim3(1), 0, stream>>>(accf, out);
}